// Round 4
// baseline (56.467 us; speedup 1.0000x reference)
//
#include <hip/hip_runtime.h>

// DistanceInfoNCE, algebraically reduced:
//   S[i] = B*sq[i] + sum_sq - 2*dot(a_i, asum) + neg_dist[i]
//
// SINGLE-KERNEL graph (1 node, no init kernel). Survives 0xAA poison without
// pre-zeroing: no accumulating atomics anywhere — every cross-block value is
// an idempotent per-block-slot store, and barriers are MAGIC-valued flags
// (release store / acquire poll, agent scope). On replay >= 2 flags are
// already MAGIC so barriers degenerate; that is value-safe because each
// replay stores bitwise-identical data (deterministic inputs).
//
// Stages (deadlock-free: each stage depends only on earlier stages):
//   A: block b computes its 16 rows' stats (kept in REGISTERS) + column
//      partials C[b][256], sq partial SQP[b]; sets F1[b].
//   R: blocks g<32 wait F1[8g..8g+8), reduce 8 C-rows -> C2[g][256], SQ2[g];
//      set F2[g].
//   B: all blocks wait F2[0..32), build asum/sum_sq (32 KB, coalesced),
//      compute per-row losses from registers, store L[b]; set F3[b].
//   F: block 0 waits all F3, sums L -> out[0].
//
// ws int/float layout:
//   F1[256] @0   F2[32] @256   F3[256] @320
//   L[256] @576  SQP[256] @832  SQ2[32] @1088
//   C[256][256] @1152   C2[32][256] @66688   (total ~300 KB)

#define BLK  256
#define GRID 256
#define MAGIC 0x1F2E3D4C

#define O_F1  0
#define O_F2  256
#define O_F3  320
#define O_L   576
#define O_SQP 832
#define O_SQ2 1088
#define O_C   1152
#define O_C2  66688
#define WS_NEED ((O_C2 + 32 * 256) * 4)

__device__ __forceinline__ float wave_reduce(float v) {
    #pragma unroll
    for (int off = 32; off > 0; off >>= 1) v += __shfl_down(v, off, 64);
    return v;
}
__device__ __forceinline__ void flag_set(int* p) {
    __hip_atomic_store(p, MAGIC, __ATOMIC_RELEASE, __HIP_MEMORY_SCOPE_AGENT);
}
__device__ __forceinline__ void flag_wait(const int* p) {
    while (__hip_atomic_load(p, __ATOMIC_ACQUIRE, __HIP_MEMORY_SCOPE_AGENT) != MAGIC)
        __builtin_amdgcn_s_sleep(1);
}
__device__ __forceinline__ void stf(float* p, float v) {
    __hip_atomic_store(p, v, __ATOMIC_RELAXED, __HIP_MEMORY_SCOPE_AGENT);
}
__device__ __forceinline__ float ldf(const float* p) {
    return __hip_atomic_load(p, __ATOMIC_RELAXED, __HIP_MEMORY_SCOPE_AGENT);
}

__global__ __launch_bounds__(BLK, 1)
void k_mono(const float4* __restrict__ A, const float4* __restrict__ P,
            const float4* __restrict__ N, float* ws, float* __restrict__ out, int B) {
    const int tid  = threadIdx.x;
    const int lane = tid & 63;
    const int wid  = tid >> 6;
    const int blk  = blockIdx.x;
    const int gw   = blk * 4 + wid;
    const float Bf = (float)B;
    int* wsi = (int*)ws;

    // ---------------- Stage A: row stats + column partials ----------------
    float4 a[4];
    float  ssq[4], spd[4], snd[4];
    float4 col = make_float4(0.f, 0.f, 0.f, 0.f);
    float  wsq = 0.0f;
    const int base = gw * 4;

    #pragma unroll
    for (int r = 0; r < 4; ++r) {
        const int i = base + r;
        a[r] = A[i * 64 + lane];
        const float4 p = P[i * 64 + lane];
        const float4 n = N[i * 64 + lane];
        col.x += a[r].x; col.y += a[r].y; col.z += a[r].z; col.w += a[r].w;
        const float dpx = a[r].x - p.x, dpy = a[r].y - p.y, dpz = a[r].z - p.z, dpw = a[r].w - p.w;
        const float dnx = a[r].x - n.x, dny = a[r].y - n.y, dnz = a[r].z - n.z, dnw = a[r].w - n.w;
        float s_sq = a[r].x * a[r].x + a[r].y * a[r].y + a[r].z * a[r].z + a[r].w * a[r].w;
        float s_pd = dpx * dpx + dpy * dpy + dpz * dpz + dpw * dpw;
        float s_nd = dnx * dnx + dny * dny + dnz * dnz + dnw * dnw;
        #pragma unroll
        for (int off = 32; off > 0; off >>= 1) {
            s_sq += __shfl_down(s_sq, off, 64);
            s_pd += __shfl_down(s_pd, off, 64);
            s_nd += __shfl_down(s_nd, off, 64);
        }
        ssq[r] = s_sq; spd[r] = s_pd; snd[r] = s_nd;
        if (lane == 0) wsq += s_sq;
    }

    __shared__ float4 ls4[4][64];
    __shared__ float  sqr[4];
    ls4[wid][lane] = col;
    if (lane == 0) sqr[wid] = wsq;
    __syncthreads();

    const float* lsf = (const float*)ls4;          // [4][256] view
    const float c = lsf[tid] + lsf[256 + tid] + lsf[512 + tid] + lsf[768 + tid];
    stf(&ws[O_C + blk * 256 + tid], c);
    if (tid == 0) stf(&ws[O_SQP + blk], sqr[0] + sqr[1] + sqr[2] + sqr[3]);
    __threadfence();
    __syncthreads();
    if (tid == 0) flag_set(&wsi[O_F1 + blk]);

    // ---------------- Stage R: 32 reducer blocks ----------------
    if (blk < 32) {
        if (tid < 8) flag_wait(&wsi[O_F1 + 8 * blk + tid]);
        __syncthreads();
        __threadfence();
        float cs = 0.0f;
        #pragma unroll
        for (int r = 0; r < 8; ++r) cs += ldf(&ws[O_C + (8 * blk + r) * 256 + tid]);
        stf(&ws[O_C2 + blk * 256 + tid], cs);
        if (tid == 0) {
            float s2 = 0.0f;
            #pragma unroll
            for (int r = 0; r < 8; ++r) s2 += ldf(&ws[O_SQP + 8 * blk + r]);
            stf(&ws[O_SQ2 + blk], s2);
        }
        __threadfence();
        __syncthreads();
        if (tid == 0) flag_set(&wsi[O_F2 + blk]);
    }

    // ---------------- Stage B: asum/sum_sq + loss ----------------
    if (tid < 32) flag_wait(&wsi[O_F2 + tid]);
    __syncthreads();
    __threadfence();

    float asum_t = 0.0f;
    #pragma unroll
    for (int g = 0; g < 32; ++g) asum_t += ldf(&ws[O_C2 + g * 256 + tid]);  // coalesced

    __shared__ float s_sq2[32];
    if (tid < 32) s_sq2[tid] = ldf(&ws[O_SQ2 + tid]);
    __shared__ float lds_asum[256];
    lds_asum[tid] = asum_t;
    __syncthreads();

    float sum_sq = 0.0f;
    #pragma unroll
    for (int g = 0; g < 32; ++g) sum_sq += s_sq2[g];
    const float4 frag = *(const float4*)&lds_asum[lane * 4];

    float wl = 0.0f;
    #pragma unroll
    for (int r = 0; r < 4; ++r) {
        float d = a[r].x * frag.x + a[r].y * frag.y + a[r].z * frag.z + a[r].w * frag.w;
        d = wave_reduce(d);
        if (lane == 0) {
            const float S  = Bf * ssq[r] + sum_sq - 2.0f * d + snd[r];
            const float ps = expf(-2.0f * spd[r]);   // /TAU, TAU=0.5
            const float ns = expf(-2.0f * S);
            wl += -logf(ps / (ps + ns + 1e-9f));
        }
    }

    __shared__ float lred[4];
    if (lane == 0) lred[wid] = wl;
    __syncthreads();
    if (tid == 0) {
        stf(&ws[O_L + blk], lred[0] + lred[1] + lred[2] + lred[3]);
        __threadfence();
        flag_set(&wsi[O_F3 + blk]);
    }

    // ---------------- Finale: block 0 sums L ----------------
    if (blk == 0) {
        flag_wait(&wsi[O_F3 + tid]);     // each thread polls its own flag
        __syncthreads();
        __threadfence();
        float v = ldf(&ws[O_L + tid]);
        v = wave_reduce(v);
        __shared__ float fred[4];
        if (lane == 0) fred[wid] = v;
        __syncthreads();
        if (tid == 0) out[0] = (fred[0] + fred[1] + fred[2] + fred[3]) * (1.0f / Bf);
    }
}

// ---------------- fallback (B != 4096): round-1 pipeline ----------------

__global__ void k_init(float* __restrict__ ws) {
    for (int i = threadIdx.x; i < 260; i += BLK) ws[i] = 0.0f;
}

__global__ void k_pass1(const float4* __restrict__ A, const float4* __restrict__ P,
                        const float4* __restrict__ N, float* __restrict__ ws, int B) {
    const int lane = threadIdx.x & 63;
    const int wid  = threadIdx.x >> 6;
    const int gwave = blockIdx.x * 4 + wid;

    float* __restrict__ sq_o = ws + 260;
    float* __restrict__ pd_o = ws + 260 + B;
    float* __restrict__ nd_o = ws + 260 + 2 * B;

    __shared__ float lsum[256];
    __shared__ float sqred[4];
    lsum[threadIdx.x] = 0.0f;
    __syncthreads();

    float4 col = make_float4(0.f, 0.f, 0.f, 0.f);
    float wave_sq = 0.0f;

    for (int i = gwave; i < B; i += GRID * 4) {
        const float4 a = A[i * 64 + lane];
        const float4 p = P[i * 64 + lane];
        const float4 n = N[i * 64 + lane];
        col.x += a.x; col.y += a.y; col.z += a.z; col.w += a.w;
        const float dpx = a.x - p.x, dpy = a.y - p.y, dpz = a.z - p.z, dpw = a.w - p.w;
        const float dnx = a.x - n.x, dny = a.y - n.y, dnz = a.z - n.z, dnw = a.w - n.w;
        float s_sq = a.x * a.x + a.y * a.y + a.z * a.z + a.w * a.w;
        float s_pd = dpx * dpx + dpy * dpy + dpz * dpz + dpw * dpw;
        float s_nd = dnx * dnx + dny * dny + dnz * dnz + dnw * dnw;
        #pragma unroll
        for (int off = 32; off > 0; off >>= 1) {
            s_sq += __shfl_down(s_sq, off, 64);
            s_pd += __shfl_down(s_pd, off, 64);
            s_nd += __shfl_down(s_nd, off, 64);
        }
        if (lane == 0) { sq_o[i] = s_sq; pd_o[i] = s_pd; nd_o[i] = s_nd; wave_sq += s_sq; }
    }

    atomicAdd(&lsum[4 * lane + 0], col.x);
    atomicAdd(&lsum[4 * lane + 1], col.y);
    atomicAdd(&lsum[4 * lane + 2], col.z);
    atomicAdd(&lsum[4 * lane + 3], col.w);
    if (lane == 0) sqred[wid] = wave_sq;
    __syncthreads();

    atomicAdd(&ws[4 + threadIdx.x], lsum[threadIdx.x]);
    if (threadIdx.x == 0)
        atomicAdd(&ws[1], sqred[0] + sqred[1] + sqred[2] + sqred[3]);
}

__global__ void k_pass2(const float4* __restrict__ A, float* __restrict__ ws, int B) {
    const int lane = threadIdx.x & 63;
    const int wid  = threadIdx.x >> 6;
    const int gwave = blockIdx.x * 4 + wid;

    const float* __restrict__ sq_i = ws + 260;
    const float* __restrict__ pd_i = ws + 260 + B;
    const float* __restrict__ nd_i = ws + 260 + 2 * B;

    const float sum_sq = ws[1];
    const float4 s = ((const float4*)(ws + 4))[lane];
    const float Bf = (float)B;

    float wave_loss = 0.0f;
    for (int i = gwave; i < B; i += GRID * 4) {
        const float4 a = A[i * 64 + lane];
        float d = a.x * s.x + a.y * s.y + a.z * s.z + a.w * s.w;
        d = wave_reduce(d);
        if (lane == 0) {
            const float S = Bf * sq_i[i] + sum_sq - 2.0f * d + nd_i[i];
            const float ps = expf(-2.0f * pd_i[i]);
            const float ns = expf(-2.0f * S);
            wave_loss += -logf(ps / (ps + ns + 1e-9f));
        }
    }

    __shared__ float lred[4];
    if (lane == 0) lred[wid] = wave_loss;
    __syncthreads();
    if (threadIdx.x == 0)
        atomicAdd(&ws[0], lred[0] + lred[1] + lred[2] + lred[3]);
}

__global__ void k_fin(const float* __restrict__ ws, float* __restrict__ out, float invB) {
    out[0] = ws[0] * invB;
}

extern "C" void kernel_launch(void* const* d_in, const int* in_sizes, int n_in,
                              void* d_out, int out_size, void* d_ws, size_t ws_size,
                              hipStream_t stream) {
    const float4* A = (const float4*)d_in[0];
    const float4* P = (const float4*)d_in[1];
    const float4* N = (const float4*)d_in[2];
    float* ws  = (float*)d_ws;
    float* out = (float*)d_out;
    const int D = 256;
    const int B = in_sizes[0] / D;   // 4096

    if (B == 4096 && ws_size >= (size_t)WS_NEED) {
        k_mono<<<GRID, BLK, 0, stream>>>(A, P, N, ws, out, B);
    } else {
        k_init <<<1, BLK, 0, stream>>>(ws);
        k_pass1<<<GRID, BLK, 0, stream>>>(A, P, N, ws, B);
        k_pass2<<<GRID, BLK, 0, stream>>>(A, ws, B);
        k_fin  <<<1, 1, 0, stream>>>(ws, out, 1.0f / (float)B);
    }
}

// Round 5
// 32.368 us; speedup vs baseline: 1.7445x; 1.7445x over previous
//
#include <hip/hip_runtime.h>

// DistanceInfoNCE, algebraically reduced:
//   S[i] = B*sq[i] + sum_sq - 2*dot(a_i, asum) + neg_dist[i]
// avoids the B x B gram matrix entirely (O(B*D) instead of O(B^2*D)).
//
// Round-1 structure restored: 4 light kernels. Measured best (31.99 us).
// R3 (2-node flag-sync) == 32.06, R4 (1-node, agent-scope fences) == 56/85 us:
// cross-block coherence inside a kernel costs far more than kernel boundaries
// on non-coherent-L2 CDNA4. This 4-kernel chain sits on the harness floor.
//
// ws layout (floats):
//   [0]        loss_sum
//   [1]        sum_sq
//   [4..259]   asum[256]        (16B aligned for float4)
//   [260..]    sq[B]
//   [260+B..]  pos_dist[B]
//   [260+2B..] neg_dist[B]

#define BLK 256
#define NBLOCKS 256
#define NWAVES (NBLOCKS * (BLK / 64))   // 1024 waves

__device__ __forceinline__ float wave_reduce(float v) {
    #pragma unroll
    for (int off = 32; off > 0; off >>= 1) v += __shfl_down(v, off, 64);
    return v;
}

__global__ void k_init(float* __restrict__ ws) {
    for (int i = threadIdx.x; i < 260; i += BLK) ws[i] = 0.0f;
}

__global__ void k_pass1(const float4* __restrict__ A, const float4* __restrict__ P,
                        const float4* __restrict__ N, float* __restrict__ ws, int B) {
    const int lane = threadIdx.x & 63;
    const int wid  = threadIdx.x >> 6;
    const int gwave = blockIdx.x * (BLK / 64) + wid;

    float* __restrict__ sq_o = ws + 260;
    float* __restrict__ pd_o = ws + 260 + B;
    float* __restrict__ nd_o = ws + 260 + 2 * B;

    __shared__ float lsum[256];   // block-level column accumulator
    __shared__ float sqred[4];
    lsum[threadIdx.x] = 0.0f;
    __syncthreads();

    float4 col = make_float4(0.f, 0.f, 0.f, 0.f);
    float wave_sq = 0.0f;

    for (int i = gwave; i < B; i += NWAVES) {
        const float4 a = A[i * 64 + lane];
        const float4 p = P[i * 64 + lane];
        const float4 n = N[i * 64 + lane];
        col.x += a.x; col.y += a.y; col.z += a.z; col.w += a.w;
        const float dpx = a.x - p.x, dpy = a.y - p.y, dpz = a.z - p.z, dpw = a.w - p.w;
        const float dnx = a.x - n.x, dny = a.y - n.y, dnz = a.z - n.z, dnw = a.w - n.w;
        float s_sq = a.x * a.x + a.y * a.y + a.z * a.z + a.w * a.w;
        float s_pd = dpx * dpx + dpy * dpy + dpz * dpz + dpw * dpw;
        float s_nd = dnx * dnx + dny * dny + dnz * dnz + dnw * dnw;
        #pragma unroll
        for (int off = 32; off > 0; off >>= 1) {
            s_sq += __shfl_down(s_sq, off, 64);
            s_pd += __shfl_down(s_pd, off, 64);
            s_nd += __shfl_down(s_nd, off, 64);
        }
        if (lane == 0) {
            sq_o[i] = s_sq;
            pd_o[i] = s_pd;
            nd_o[i] = s_nd;
            wave_sq += s_sq;
        }
    }

    // per-block column reduction in LDS (4 waves collide -> LDS atomics, cheap)
    atomicAdd(&lsum[4 * lane + 0], col.x);
    atomicAdd(&lsum[4 * lane + 1], col.y);
    atomicAdd(&lsum[4 * lane + 2], col.z);
    atomicAdd(&lsum[4 * lane + 3], col.w);
    if (lane == 0) sqred[wid] = wave_sq;
    __syncthreads();

    atomicAdd(&ws[4 + threadIdx.x], lsum[threadIdx.x]);   // one global atomic/col/block
    if (threadIdx.x == 0)
        atomicAdd(&ws[1], sqred[0] + sqred[1] + sqred[2] + sqred[3]);
}

__global__ void k_pass2(const float4* __restrict__ A, float* __restrict__ ws, int B) {
    const int lane = threadIdx.x & 63;
    const int wid  = threadIdx.x >> 6;
    const int gwave = blockIdx.x * (BLK / 64) + wid;

    const float* __restrict__ sq_i = ws + 260;
    const float* __restrict__ pd_i = ws + 260 + B;
    const float* __restrict__ nd_i = ws + 260 + 2 * B;

    const float sum_sq = ws[1];
    const float4 s = ((const float4*)(ws + 4))[lane];   // asum fragment, hoisted
    const float Bf = (float)B;

    float wave_loss = 0.0f;
    for (int i = gwave; i < B; i += NWAVES) {
        const float4 a = A[i * 64 + lane];
        float d = a.x * s.x + a.y * s.y + a.z * s.z + a.w * s.w;
        d = wave_reduce(d);
        if (lane == 0) {
            const float S = Bf * sq_i[i] + sum_sq - 2.0f * d + nd_i[i];
            const float pos_sim = expf(-2.0f * pd_i[i]);   // /TAU, TAU=0.5
            const float neg_sim = expf(-2.0f * S);
            const float loss = -logf(pos_sim / (pos_sim + neg_sim + 1e-9f));
            wave_loss += loss;
        }
    }

    __shared__ float lred[4];
    if (lane == 0) lred[wid] = wave_loss;
    __syncthreads();
    if (threadIdx.x == 0)
        atomicAdd(&ws[0], lred[0] + lred[1] + lred[2] + lred[3]);
}

__global__ void k_fin(const float* __restrict__ ws, float* __restrict__ out, float invB) {
    out[0] = ws[0] * invB;   // invB = 1/4096 is a power of 2: exact, == mean
}

extern "C" void kernel_launch(void* const* d_in, const int* in_sizes, int n_in,
                              void* d_out, int out_size, void* d_ws, size_t ws_size,
                              hipStream_t stream) {
    const float4* A = (const float4*)d_in[0];
    const float4* P = (const float4*)d_in[1];
    const float4* N = (const float4*)d_in[2];
    float* ws = (float*)d_ws;
    float* out = (float*)d_out;
    const int D = 256;
    const int B = in_sizes[0] / D;   // 4096

    k_init <<<1, BLK, 0, stream>>>(ws);
    k_pass1<<<NBLOCKS, BLK, 0, stream>>>(A, P, N, ws, B);
    k_pass2<<<NBLOCKS, BLK, 0, stream>>>(A, ws, B);
    k_fin  <<<1, 1, 0, stream>>>(ws, out, 1.0f / (float)B);
}